// Round 4
// baseline (556.229 us; speedup 1.0000x reference)
//
#include <hip/hip_runtime.h>
#include <hip/hip_bf16.h>
#include <math.h>

#define TLEN 1024
#define HDIM 2048
#define NHEAD 32
#define HSZ 64
#define THE (TLEN * HDIM)
#define NC 16          // scan chunks
#define CT (TLEN / NC) // 64 timesteps per chunk

typedef __attribute__((ext_vector_type(8))) short bf16x8;
typedef __attribute__((ext_vector_type(4))) float f32x4;

__device__ __forceinline__ float waveRedSum(float v) {
#pragma unroll
  for (int off = 32; off > 0; off >>= 1) v += __shfl_xor(v, off, 64);
  return v;
}

__device__ __forceinline__ void gll16(const __hip_bfloat16* g, __hip_bfloat16* l) {
  __builtin_amdgcn_global_load_lds(
      (const __attribute__((address_space(1))) void*)g,
      (__attribute__((address_space(3))) void*)l, 16, 0, 0);
}

// ---------- weight convert + transpose: src f32 [R][C] -> dst bf16 [C][R] ----------
struct TrArgs {
  const float* src[8];
  __hip_bfloat16* dst[8];
  int R[8];
  int C[8];
};

__global__ __launch_bounds__(256) void transp_kernel(TrArgs ta) {
  const int z = blockIdx.z;
  const int R = ta.R[z], C = ta.C[z];
  const int c0 = blockIdx.x * 32, r0 = blockIdx.y * 32;
  if (c0 >= C || r0 >= R) return;
  __shared__ float tile[32][33];
  const int tx = threadIdx.x & 31, ty = threadIdx.x >> 5;
  const float* src = ta.src[z];
  __hip_bfloat16* dst = ta.dst[z];
#pragma unroll
  for (int i = 0; i < 4; i++)
    tile[ty + i * 8][tx] = src[(size_t)(r0 + ty + i * 8) * C + c0 + tx];
  __syncthreads();
#pragma unroll
  for (int i = 0; i < 4; i++)
    dst[(size_t)(c0 + ty + i * 8) * R + r0 + tx] = __float2bfloat16(tile[tx][ty + i * 8]);
}

// ---------- LayerNorm (row) + state1_out ----------
__global__ __launch_bounds__(256) void ln1_kernel(const float* __restrict__ x,
                                                  const float* __restrict__ w,
                                                  const float* __restrict__ b,
                                                  float* __restrict__ xl,
                                                  float* __restrict__ s1out) {
  const int t = blockIdx.x;
  const int tid = threadIdx.x;
  const int wid = tid >> 6, lane = tid & 63;
  const float4* xr = (const float4*)(x + (size_t)t * HDIM);
  float4 a = xr[tid];
  float4 c = xr[tid + 256];
  float va[8] = {a.x, a.y, a.z, a.w, c.x, c.y, c.z, c.w};
  float sum = 0.f;
#pragma unroll
  for (int i = 0; i < 8; i++) sum += va[i];
  sum = waveRedSum(sum);
  __shared__ float red[8];
  if (lane == 0) red[wid] = sum;
  __syncthreads();
  const float mu = (red[0] + red[1] + red[2] + red[3]) * (1.f / HDIM);
  float vs = 0.f;
#pragma unroll
  for (int i = 0; i < 8; i++) { float d = va[i] - mu; vs += d * d; }
  vs = waveRedSum(vs);
  if (lane == 0) red[4 + wid] = vs;
  __syncthreads();
  const float rstd = rsqrtf((red[4] + red[5] + red[6] + red[7]) * (1.f / HDIM) + 1e-5f);
  float* xrow = xl + (size_t)t * HDIM;
#pragma unroll
  for (int i = 0; i < 8; i++) {
    const int idx = (i < 4) ? (4 * tid + i) : (1024 + 4 * tid + (i - 4));
    const float o = (va[i] - mu) * rstd * w[idx] + b[idx];
    xrow[idx] = o;
    if (t == TLEN - 1) s1out[idx] = o;
  }
}

// ---------- token shift: xxx = xl + (past - xl) * time_maa_x ----------
__global__ __launch_bounds__(256) void tokshift_kernel(const float* __restrict__ xl,
                                                       const float* __restrict__ s1,
                                                       const float* __restrict__ tmx,
                                                       __hip_bfloat16* __restrict__ xxx) {
  const int t = blockIdx.x;
  const int h = blockIdx.y * 256 + threadIdx.x;
  const float cur = xl[(size_t)t * HDIM + h];
  const float past = (t > 0) ? xl[(size_t)(t - 1) * HDIM + h] : s1[h];
  xxx[(size_t)t * HDIM + h] = __float2bfloat16(cur + (past - cur) * tmx[h]);
}

// ---------- mix: x5[f] = xl + sx * (t5[f] @ w2[f] + time_maa[f]) ----------
__global__ __launch_bounds__(256) void mix_kernel(const float* __restrict__ t5,
                                                  const float* __restrict__ xl,
                                                  const float* __restrict__ s1,
                                                  const float* __restrict__ w2,
                                                  const float* __restrict__ maa,
                                                  __hip_bfloat16* __restrict__ x5b) {
  const int h = blockIdx.x * 256 + threadIdx.x;
  const int t0 = blockIdx.y * 8;
  __shared__ float t5L[8 * 160];
  for (int i = threadIdx.x; i < 8 * 160; i += 256) {
    const int rr = i / 160, cc = i - rr * 160;
    t5L[i] = t5[(size_t)(t0 + rr) * 160 + cc];
  }
  __syncthreads();
  float mixv[8][5];
#pragma unroll
  for (int ts = 0; ts < 8; ts++)
#pragma unroll
    for (int f = 0; f < 5; f++) mixv[ts][f] = 0.f;
#pragma unroll
  for (int f = 0; f < 5; f++) {
#pragma unroll 4
    for (int m = 0; m < 32; m++) {
      const float w2v = w2[(size_t)(f * 32 + m) * HDIM + h];
#pragma unroll
      for (int ts = 0; ts < 8; ts++) mixv[ts][f] += t5L[ts * 160 + f * 32 + m] * w2v;
    }
  }
#pragma unroll
  for (int ts = 0; ts < 8; ts++) {
    const int t = t0 + ts;
    const float cur = xl[(size_t)t * HDIM + h];
    const float past = (t > 0) ? xl[(size_t)(t - 1) * HDIM + h] : s1[h];
    const float sx = past - cur;
#pragma unroll
    for (int f = 0; f < 5; f++) {
      const float v = cur + sx * (mixv[ts][f] + maa[(size_t)f * HDIM + h]);
      x5b[(size_t)f * THE + (size_t)t * HDIM + h] = __float2bfloat16(v);
    }
  }
}

// ---------- batched MFMA GEMM: C[z] = epi( A[z](MxK) @ Bt[z](NxK)^T ) ----------
// epi: 0=bf16 none, 1=bf16 silu, 2=f32 tanh, 3=bf16 tanh, 4=f32 td(+p,clip,exp-exp), 5=f32 +residual
struct GemmArgs {
  const __hip_bfloat16* A[4];
  const __hip_bfloat16* B[4];
  void* C[4];
  const float* aux[4];
  int epi[4];
  int M, N, K;
};

__global__ __launch_bounds__(256) void gemm_bt(GemmArgs ga) {
  const int z = blockIdx.z;
  const __hip_bfloat16* __restrict__ A = ga.A[z];
  const __hip_bfloat16* __restrict__ Bt = ga.B[z];
  const int N = ga.N, K = ga.K;
  const int epi = ga.epi[z];
  const float* __restrict__ aux = ga.aux[z];
  void* Cz = ga.C[z];

  __shared__ __align__(16) __hip_bfloat16 As[128 * 32];
  __shared__ __align__(16) __hip_bfloat16 Bs[128 * 32];

  const int tid = threadIdx.x;
  const int wid = tid >> 6;
  const int lane = tid & 63;

  // XCD-aware swizzle for the 8x16 grids: cluster all 8 m-blocks of one
  // n-panel onto a single XCD so the B panel stays L2-resident.
  int bx = blockIdx.x, by = blockIdx.y;
  if (gridDim.x == 8 && gridDim.y == 16) {
    const int flat = bx + 8 * by;  // 0..127
    const int xcd = flat & 7, rem = flat >> 3;
    bx = rem & 7;
    by = xcd + 8 * (rem >> 3);
  }
  const int m0 = bx * 128;
  const int n0 = by * 128;
  const int wr = wid >> 1, wc = wid & 1;

  const int rsub = lane >> 2;   // 0..15
  const int chunk = lane & 3;   // 0..3
  const int ca = 2 * wid;       // this wave's staging calls: ca, ca+1

  const int arow0 = ca * 16 + rsub;
  const int arow1 = arow0 + 16;
  int brow0 = n0 + arow0; if (brow0 > N - 1) brow0 = N - 1;
  int brow1 = n0 + arow1; if (brow1 > N - 1) brow1 = N - 1;

  const __hip_bfloat16* aSrc0 = A + (size_t)(m0 + arow0) * K + chunk * 8;
  const __hip_bfloat16* aSrc1 = A + (size_t)(m0 + arow1) * K + chunk * 8;
  const __hip_bfloat16* bSrc0 = Bt + (size_t)brow0 * K + chunk * 8;
  const __hip_bfloat16* bSrc1 = Bt + (size_t)brow1 * K + chunk * 8;

  f32x4 acc[4][4];
#pragma unroll
  for (int m = 0; m < 4; m++)
#pragma unroll
    for (int n = 0; n < 4; n++) acc[m][n] = 0.f;

  const int lr = lane & 15;
  const int lk8 = (lane >> 4) * 8;
  const int aoff = (wr * 64 + lr) * 32 + lk8;
  const int boff = (wc * 64 + lr) * 32 + lk8;

  for (int kt = 0; kt < K; kt += 32) {
    gll16(aSrc0 + kt, &As[ca * 512]);
    gll16(aSrc1 + kt, &As[ca * 512 + 512]);
    gll16(bSrc0 + kt, &Bs[ca * 512]);
    gll16(bSrc1 + kt, &Bs[ca * 512 + 512]);
    __syncthreads();
    bf16x8 af[4], bfv[4];
#pragma unroll
    for (int m = 0; m < 4; m++) af[m] = *(const bf16x8*)&As[aoff + m * 16 * 32];
#pragma unroll
    for (int n = 0; n < 4; n++) bfv[n] = *(const bf16x8*)&Bs[boff + n * 16 * 32];
#pragma unroll
    for (int m = 0; m < 4; m++)
#pragma unroll
      for (int n = 0; n < 4; n++)
        acc[m][n] = __builtin_amdgcn_mfma_f32_16x16x32_bf16(af[m], bfv[n], acc[m][n], 0, 0, 0);
    __syncthreads();
  }

  const int r4 = (lane >> 4) * 4;
#pragma unroll
  for (int m = 0; m < 4; m++) {
#pragma unroll
    for (int n = 0; n < 4; n++) {
      const int gn = n0 + wc * 64 + n * 16 + lr;
      if (gn < N) {
#pragma unroll
        for (int r = 0; r < 4; r++) {
          const int gm = m0 + wr * 64 + m * 16 + r4 + r;
          const size_t idx = (size_t)gm * N + gn;
          const float v = acc[m][n][r];
          switch (epi) {
            case 0: ((__hip_bfloat16*)Cz)[idx] = __float2bfloat16(v); break;
            case 1: ((__hip_bfloat16*)Cz)[idx] = __float2bfloat16(v / (1.f + expf(-v))); break;
            case 2: ((float*)Cz)[idx] = tanhf(v); break;
            case 3: ((__hip_bfloat16*)Cz)[idx] = __float2bfloat16(tanhf(v)); break;
            case 4: {
              float wv = v + aux[gn];
              wv = fminf(fmaxf(wv, -9.72f), 2.27f);
              ((float*)Cz)[idx] = expf(-expf(wv));
            } break;
            case 5: ((float*)Cz)[idx] = v + aux[idx]; break;
          }
        }
      }
    }
  }
}

// ---------- repack: krp[h][t][j] = k|r<<16 ; tdp[h][t][j] = td ----------
__global__ __launch_bounds__(256) void repack_kernel(const __hip_bfloat16* __restrict__ kb,
                                                     const __hip_bfloat16* __restrict__ rb,
                                                     const float* __restrict__ td,
                                                     unsigned* __restrict__ krp,
                                                     float* __restrict__ tdp) {
  const int idx = blockIdx.x * 256 + threadIdx.x;  // [h][t][j]
  const int j = idx & 63;
  const int t = (idx >> 6) & (TLEN - 1);
  const int h = idx >> 16;
  const size_t src = (size_t)t * HDIM + h * HSZ + j;
  const unsigned kk = *(const unsigned short*)&kb[src];
  const unsigned rr = *(const unsigned short*)&rb[src];
  krp[idx] = kk | (rr << 16);
  tdp[idx] = td[src];
}

// ---------- chunk decay products: Ptot[c][h][j] = prod_{t in chunk} td ----------
__global__ __launch_bounds__(64) void scanP_kernel(const float* __restrict__ tdp,
                                                   float* __restrict__ Ptot) {
  const int flat = blockIdx.x;            // NH*NC = 512
  const int xcd = flat & 7;
  const int inner = flat >> 3;            // 0..63
  const int h = xcd * 4 + (inner >> 4);
  const int c = inner & 15;
  const int j = threadIdx.x;
  const float* tdb = tdp + ((size_t)h * TLEN + c * CT) * 64 + j;
  float P = 1.f;
#pragma unroll 8
  for (int t = 0; t < CT; t++) P *= tdb[t * 64];
  Ptot[((size_t)c * NHEAD + h) * HSZ + j] = P;
}

// ---------- S1: per-chunk local state qT (zero-init scan, no outputs) ----------
// lane = i; j serialized in registers. s[j] updates only: 2 FMA-class ops/j/t.
__global__ __launch_bounds__(64) void scan_q_kernel(const unsigned* __restrict__ krp,
                                                    const float* __restrict__ tdp,
                                                    const __hip_bfloat16* __restrict__ vb,
                                                    float* __restrict__ qT) {
  const int flat = blockIdx.x;            // 512
  const int xcd = flat & 7;
  const int inner = flat >> 3;
  const int h = xcd * 4 + (inner >> 4);
  const int c = inner & 15;
  const int i = threadIdx.x;              // lane = output row
  float s[64];
#pragma unroll
  for (int j = 0; j < 64; j++) s[j] = 0.f;

  const unsigned* krb = krp + ((size_t)h * TLEN + c * CT) * 64;
  const float* tdb = tdp + ((size_t)h * TLEN + c * CT) * 64;
  const __hip_bfloat16* vbb = vb + (size_t)(c * CT) * HDIM + h * HSZ + i;

  for (int t = 0; t < CT; t++) {
    const float vi = __bfloat162float(vbb[(size_t)t * HDIM]);
#pragma unroll
    for (int g = 0; g < 4; g++) {
      unsigned krw[16];
      float tdw[16];
#pragma unroll
      for (int q = 0; q < 16; q++) {
        krw[q] = krb[t * 64 + g * 16 + q];
        tdw[q] = tdb[t * 64 + g * 16 + q];
      }
#pragma unroll
      for (int q = 0; q < 16; q++) {
        const int j = g * 16 + q;
        const float kj = __builtin_bit_cast(float, krw[q] << 16);
        const float kv = vi * kj;
        s[j] = fmaf(s[j], tdw[q], kv);
      }
    }
  }
  float4* qrow = (float4*)(qT + ((((size_t)c * NHEAD + h) * HSZ + i) * HSZ));
#pragma unroll
  for (int j4 = 0; j4 < 16; j4++)
    qrow[j4] = make_float4(s[4 * j4], s[4 * j4 + 1], s[4 * j4 + 2], s[4 * j4 + 3]);
}

// ---------- S2: sequential chunk combine (tiny) ----------
__global__ __launch_bounds__(64) void scan_s_kernel(const float* __restrict__ qT,
                                                    const float* __restrict__ Ptot,
                                                    const float* __restrict__ s2in,
                                                    float* __restrict__ s0c,
                                                    float* __restrict__ s2out) {
  const int h = blockIdx.x, i = blockIdx.y, j = threadIdx.x;
  float s = s2in[((size_t)h * HSZ + i) * HSZ + j];
#pragma unroll
  for (int c = 0; c < NC; c++) {
    const size_t base = (((size_t)c * NHEAD + h) * HSZ + i) * HSZ + j;
    s0c[base] = s;
    s = fmaf(s, Ptot[((size_t)c * NHEAD + h) * HSZ + j], qT[base]);
  }
  s2out[((size_t)h * HSZ + i) * HSZ + j] = s;
}

// ---------- S3: main per-chunk scan with correct s0; lane = i, no shuffles ----------
__global__ __launch_bounds__(64) void scan_kernel(const unsigned* __restrict__ krp,
                                                  const float* __restrict__ tdp,
                                                  const __hip_bfloat16* __restrict__ vb,
                                                  const float* __restrict__ tf,
                                                  const float* __restrict__ s0c,
                                                  float* __restrict__ wkv) {
  const int flat = blockIdx.x;            // 512
  const int xcd = flat & 7;
  const int inner = flat >> 3;
  const int h = xcd * 4 + (inner >> 4);
  const int c = inner & 15;
  const int i = threadIdx.x;              // lane = output row

  float s[64];
  const float4* srow = (const float4*)(s0c + ((((size_t)c * NHEAD + h) * HSZ + i) * HSZ));
#pragma unroll
  for (int j4 = 0; j4 < 16; j4++) {
    const float4 v4 = srow[j4];
    s[4 * j4] = v4.x; s[4 * j4 + 1] = v4.y; s[4 * j4 + 2] = v4.z; s[4 * j4 + 3] = v4.w;
  }
  float tfv[64];
#pragma unroll
  for (int j = 0; j < 64; j++) tfv[j] = tf[h * HSZ + j];

  const unsigned* krb = krp + ((size_t)h * TLEN + c * CT) * 64;
  const float* tdb = tdp + ((size_t)h * TLEN + c * CT) * 64;
  const __hip_bfloat16* vbb = vb + (size_t)(c * CT) * HDIM + h * HSZ + i;
  float* wb = wkv + (size_t)(c * CT) * HDIM + h * HSZ + i;

  for (int t = 0; t < CT; t++) {
    const float vi = __bfloat162float(vbb[(size_t)t * HDIM]);
    float p0 = 0.f, p1 = 0.f;
#pragma unroll
    for (int g = 0; g < 4; g++) {
      unsigned krw[16];
      float tdw[16];
#pragma unroll
      for (int q = 0; q < 16; q++) {
        krw[q] = krb[t * 64 + g * 16 + q];
        tdw[q] = tdb[t * 64 + g * 16 + q];
      }
#pragma unroll
      for (int q = 0; q < 16; q++) {
        const int j = g * 16 + q;
        const float kj = __builtin_bit_cast(float, krw[q] << 16);
        const float rj = __builtin_bit_cast(float, krw[q] & 0xffff0000u);
        const float kv = vi * kj;
        const float u = fmaf(tfv[j], kv, s[j]);
        if (q & 1) p1 = fmaf(rj, u, p1); else p0 = fmaf(rj, u, p0);
        s[j] = fmaf(s[j], tdw[q], kv);
      }
    }
    wb[(size_t)t * HDIM] = p0 + p1;
  }
}

// ---------- group norm over HS + scale/bias + gate ----------
__global__ __launch_bounds__(256) void gnorm_kernel(const float* __restrict__ wkv,
                                                    const __hip_bfloat16* __restrict__ gb,
                                                    const float* __restrict__ lnw,
                                                    const float* __restrict__ lnb,
                                                    __hip_bfloat16* __restrict__ yA) {
  const int t = blockIdx.x;
  const int wid = threadIdx.x >> 6, j = threadIdx.x & 63;
  const int h = blockIdx.y * 4 + wid;
  const size_t idx = (size_t)t * HDIM + h * HSZ + j;
  const float v = wkv[idx];
  const float mu = waveRedSum(v) * (1.f / HSZ);
  const float d = v - mu;
  const float var = waveRedSum(d * d) * (1.f / HSZ);
  float y = d * rsqrtf(var + 1e-5f);
  y = y * lnw[h * HSZ + j] + lnb[h * HSZ + j];
  y *= __bfloat162float(gb[idx]);
  yA[idx] = __float2bfloat16(y);
}

extern "C" void kernel_launch(void* const* d_in, const int* in_sizes, int n_in,
                              void* d_out, int out_size, void* d_ws, size_t ws_size,
                              hipStream_t stream) {
  (void)in_sizes; (void)n_in; (void)out_size; (void)ws_size;

  const float* x    = (const float*)d_in[0];
  const float* s1   = (const float*)d_in[1];
  const float* s2   = (const float*)d_in[2];
  const float* ln1w = (const float*)d_in[3];
  const float* ln1b = (const float*)d_in[4];
  const float* tmx  = (const float*)d_in[5];
  const float* tmaa = (const float*)d_in[6];
  const float* w1   = (const float*)d_in[7];
  const float* w2   = (const float*)d_in[8];
  const float* dw1  = (const float*)d_in[9];
  const float* dw2  = (const float*)d_in[10];
  const float* dp   = (const float*)d_in[11];
  const float* tf   = (const float*)d_in[12];
  const float* Wr   = (const float*)d_in[13];
  const float* Wk   = (const float*)d_in[14];
  const float* Wv   = (const float*)d_in[15];
  const float* Wg   = (const float*)d_in[16];
  const float* Wo   = (const float*)d_in[17];
  const float* lnxw = (const float*)d_in[18];
  const float* lnxb = (const float*)d_in[19];

  float* out0  = (float*)d_out;
  float* s1out = out0 + (size_t)TLEN * HDIM;
  float* s2out = s1out + HDIM;

  char* wp = (char*)d_ws;
  size_t off = 0;
  auto carve = [&](size_t bytes) -> void* {
    void* r = wp + off;
    off += (bytes + 255) & ~(size_t)255;
    return r;
  };

  __hip_bfloat16* wrt  = (__hip_bfloat16*)carve((size_t)HDIM * HDIM * 2);
  __hip_bfloat16* wkt  = (__hip_bfloat16*)carve((size_t)HDIM * HDIM * 2);
  __hip_bfloat16* wvt  = (__hip_bfloat16*)carve((size_t)HDIM * HDIM * 2);
  __hip_bfloat16* wgt  = (__hip_bfloat16*)carve((size_t)HDIM * HDIM * 2);
  __hip_bfloat16* wot  = (__hip_bfloat16*)carve((size_t)HDIM * HDIM * 2);
  __hip_bfloat16* w1t  = (__hip_bfloat16*)carve((size_t)160 * HDIM * 2);
  __hip_bfloat16* dw1t = (__hip_bfloat16*)carve((size_t)64 * HDIM * 2);
  __hip_bfloat16* dw2t = (__hip_bfloat16*)carve((size_t)HDIM * 64 * 2);
  float* xl            = (float*)carve((size_t)THE * 4);
  __hip_bfloat16* xxx  = (__hip_bfloat16*)carve((size_t)THE * 2);
  float* t5            = (float*)carve((size_t)TLEN * 160 * 4);
  __hip_bfloat16* x5b  = (__hip_bfloat16*)carve((size_t)5 * THE * 2);
  __hip_bfloat16* rb   = (__hip_bfloat16*)carve((size_t)THE * 2);
  __hip_bfloat16* kb   = (__hip_bfloat16*)carve((size_t)THE * 2);
  __hip_bfloat16* vb   = (__hip_bfloat16*)carve((size_t)THE * 2);
  __hip_bfloat16* gb   = (__hip_bfloat16*)carve((size_t)THE * 2);
  __hip_bfloat16* tw   = (__hip_bfloat16*)carve((size_t)TLEN * 64 * 2);
  float* td            = (float*)carve((size_t)THE * 4);
  float* wkv           = (float*)carve((size_t)THE * 4);
  __hip_bfloat16* yA   = (__hip_bfloat16*)carve((size_t)THE * 2);

  // Scan-stage buffers alias dead regions (zero extra workspace):
  //   krp (8MB) + tdp (8MB) <- x5b (20MB, dead after G5)
  //   qT  (8MB)             <- xl  (dead after mix)
  //   s0c (8MB)             <- td  (dead after repack)
  //   Ptot (128KB)          <- tw  (dead after G5)
  unsigned* krp = (unsigned*)x5b;
  float* tdp    = (float*)((char*)x5b + (size_t)NHEAD * TLEN * 64 * 4);
  float* qT     = (float*)xl;
  float* s0c    = (float*)td;
  float* Ptot   = (float*)tw;

  // K0: convert + transpose all GEMM weights to bf16 [N][K]
  TrArgs ta;
  const float* srcs[8] = {Wr, Wk, Wv, Wg, Wo, w1, dw1, dw2};
  __hip_bfloat16* dsts[8] = {wrt, wkt, wvt, wgt, wot, w1t, dw1t, dw2t};
  const int Rs[8] = {HDIM, HDIM, HDIM, HDIM, HDIM, HDIM, HDIM, 64};
  const int Cs[8] = {HDIM, HDIM, HDIM, HDIM, HDIM, 160, 64, HDIM};
  for (int z = 0; z < 8; z++) { ta.src[z] = srcs[z]; ta.dst[z] = dsts[z]; ta.R[z] = Rs[z]; ta.C[z] = Cs[z]; }
  transp_kernel<<<dim3(64, 64, 8), 256, 0, stream>>>(ta);

  // K1: layernorm
  ln1_kernel<<<dim3(TLEN), 256, 0, stream>>>(x, ln1w, ln1b, xl, s1out);

  // K2: token shift -> xxx (bf16)
  tokshift_kernel<<<dim3(TLEN, HDIM / 256), 256, 0, stream>>>(xl, s1, tmx, xxx);

  // G1: t5 = tanh(xxx @ w1)  (M=1024, N=160, K=2048)
  {
    GemmArgs g{};
    g.A[0] = xxx; g.B[0] = w1t; g.C[0] = t5; g.aux[0] = nullptr; g.epi[0] = 2;
    g.M = TLEN; g.N = 160; g.K = HDIM;
    gemm_bt<<<dim3(TLEN / 128, 2, 1), 256, 0, stream>>>(g);
  }

  // K4: mix + x5 (5 planes, bf16)
  mix_kernel<<<dim3(HDIM / 256, TLEN / 8), 256, 0, stream>>>(t5, xl, s1, w2, tmaa, x5b);

  // G2: r, k, v, g  (batched z=4)
  {
    GemmArgs g{};
    g.A[0] = x5b + (size_t)3 * THE; g.B[0] = wrt; g.C[0] = rb; g.epi[0] = 0;
    g.A[1] = x5b + (size_t)1 * THE; g.B[1] = wkt; g.C[1] = kb; g.epi[1] = 0;
    g.A[2] = x5b + (size_t)2 * THE; g.B[2] = wvt; g.C[2] = vb; g.epi[2] = 0;
    g.A[3] = x5b + (size_t)4 * THE; g.B[3] = wgt; g.C[3] = gb; g.epi[3] = 1;
    g.M = TLEN; g.N = HDIM; g.K = HDIM;
    gemm_bt<<<dim3(TLEN / 128, HDIM / 128, 4), 256, 0, stream>>>(g);
  }

  // G4: tw = tanh(mw @ dw1)  (N=64)
  {
    GemmArgs g{};
    g.A[0] = x5b; g.B[0] = dw1t; g.C[0] = tw; g.epi[0] = 3;
    g.M = TLEN; g.N = 64; g.K = HDIM;
    gemm_bt<<<dim3(TLEN / 128, 1, 1), 256, 0, stream>>>(g);
  }

  // G5: td = exp(-exp(clip(tw @ dw2 + p)))  (K=64)
  {
    GemmArgs g{};
    g.A[0] = tw; g.B[0] = dw2t; g.C[0] = td; g.aux[0] = dp; g.epi[0] = 4;
    g.M = TLEN; g.N = HDIM; g.K = 64;
    gemm_bt<<<dim3(TLEN / 128, HDIM / 128, 1), 256, 0, stream>>>(g);
  }

  // K5: pack k,r -> krp ; td -> tdp (both [h][t][j])
  repack_kernel<<<dim3((NHEAD * TLEN * 64) / 256), 256, 0, stream>>>(kb, rb, td, krp, tdp);

  // Scan stage: P-products, local q, sequential combine, main pass
  scanP_kernel<<<dim3(NHEAD * NC), 64, 0, stream>>>(tdp, Ptot);
  scan_q_kernel<<<dim3(NHEAD * NC), 64, 0, stream>>>(krp, tdp, vb, qT);
  scan_s_kernel<<<dim3(NHEAD, HSZ), 64, 0, stream>>>(qT, Ptot, s2, s0c, s2out);
  scan_kernel<<<dim3(NHEAD * NC), 64, 0, stream>>>(krp, tdp, vb, tf, s0c, wkv);

  // K7: group-norm + gate -> yA (bf16)
  gnorm_kernel<<<dim3(TLEN, NHEAD / 4), 256, 0, stream>>>(wkv, gb, lnxw, lnxb, yA);

  // G6: out = x + yA @ W_o
  {
    GemmArgs g{};
    g.A[0] = yA; g.B[0] = wot; g.C[0] = out0; g.aux[0] = x; g.epi[0] = 5;
    g.M = TLEN; g.N = HDIM; g.K = HDIM;
    gemm_bt<<<dim3(TLEN / 128, HDIM / 128, 1), 256, 0, stream>>>(g);
  }
}

// Round 5
// 406.750 us; speedup vs baseline: 1.3675x; 1.3675x over previous
//
#include <hip/hip_runtime.h>
#include <hip/hip_bf16.h>
#include <math.h>

#define TLEN 1024
#define HDIM 2048
#define NHEAD 32
#define HSZ 64
#define THE (TLEN * HDIM)
#define NC 32          // scan chunks
#define CT (TLEN / NC) // 32 timesteps per chunk

typedef __attribute__((ext_vector_type(8))) short bf16x8;
typedef __attribute__((ext_vector_type(4))) float f32x4;

__device__ __forceinline__ float waveRedSum(float v) {
#pragma unroll
  for (int off = 32; off > 0; off >>= 1) v += __shfl_xor(v, off, 64);
  return v;
}

__device__ __forceinline__ void gll16(const __hip_bfloat16* g, __hip_bfloat16* l) {
  __builtin_amdgcn_global_load_lds(
      (const __attribute__((address_space(1))) void*)g,
      (__attribute__((address_space(3))) void*)l, 16, 0, 0);
}

// ---------- weight convert + transpose: src f32 [R][C] -> dst bf16 [C][R] ----------
struct TrArgs {
  const float* src[8];
  __hip_bfloat16* dst[8];
  int R[8];
  int C[8];
};

__global__ __launch_bounds__(256) void transp_kernel(TrArgs ta) {
  const int z = blockIdx.z;
  const int R = ta.R[z], C = ta.C[z];
  const int c0 = blockIdx.x * 32, r0 = blockIdx.y * 32;
  if (c0 >= C || r0 >= R) return;
  __shared__ float tile[32][33];
  const int tx = threadIdx.x & 31, ty = threadIdx.x >> 5;
  const float* src = ta.src[z];
  __hip_bfloat16* dst = ta.dst[z];
#pragma unroll
  for (int i = 0; i < 4; i++)
    tile[ty + i * 8][tx] = src[(size_t)(r0 + ty + i * 8) * C + c0 + tx];
  __syncthreads();
#pragma unroll
  for (int i = 0; i < 4; i++)
    dst[(size_t)(c0 + ty + i * 8) * R + r0 + tx] = __float2bfloat16(tile[tx][ty + i * 8]);
}

// ---------- LayerNorm (row) + state1_out ----------
__global__ __launch_bounds__(256) void ln1_kernel(const float* __restrict__ x,
                                                  const float* __restrict__ w,
                                                  const float* __restrict__ b,
                                                  float* __restrict__ xl,
                                                  float* __restrict__ s1out) {
  const int t = blockIdx.x;
  const int tid = threadIdx.x;
  const int wid = tid >> 6, lane = tid & 63;
  const float4* xr = (const float4*)(x + (size_t)t * HDIM);
  float4 a = xr[tid];
  float4 c = xr[tid + 256];
  float va[8] = {a.x, a.y, a.z, a.w, c.x, c.y, c.z, c.w};
  float sum = 0.f;
#pragma unroll
  for (int i = 0; i < 8; i++) sum += va[i];
  sum = waveRedSum(sum);
  __shared__ float red[8];
  if (lane == 0) red[wid] = sum;
  __syncthreads();
  const float mu = (red[0] + red[1] + red[2] + red[3]) * (1.f / HDIM);
  float vs = 0.f;
#pragma unroll
  for (int i = 0; i < 8; i++) { float d = va[i] - mu; vs += d * d; }
  vs = waveRedSum(vs);
  if (lane == 0) red[4 + wid] = vs;
  __syncthreads();
  const float rstd = rsqrtf((red[4] + red[5] + red[6] + red[7]) * (1.f / HDIM) + 1e-5f);
  float* xrow = xl + (size_t)t * HDIM;
#pragma unroll
  for (int i = 0; i < 8; i++) {
    const int idx = (i < 4) ? (4 * tid + i) : (1024 + 4 * tid + (i - 4));
    const float o = (va[i] - mu) * rstd * w[idx] + b[idx];
    xrow[idx] = o;
    if (t == TLEN - 1) s1out[idx] = o;
  }
}

// ---------- token shift: xxx = xl + (past - xl) * time_maa_x ----------
__global__ __launch_bounds__(256) void tokshift_kernel(const float* __restrict__ xl,
                                                       const float* __restrict__ s1,
                                                       const float* __restrict__ tmx,
                                                       __hip_bfloat16* __restrict__ xxx) {
  const int t = blockIdx.x;
  const int h = blockIdx.y * 256 + threadIdx.x;
  const float cur = xl[(size_t)t * HDIM + h];
  const float past = (t > 0) ? xl[(size_t)(t - 1) * HDIM + h] : s1[h];
  xxx[(size_t)t * HDIM + h] = __float2bfloat16(cur + (past - cur) * tmx[h]);
}

// ---------- mix: x5[f] = xl + sx * (t5[f] @ w2[f] + time_maa[f]) ----------
__global__ __launch_bounds__(256) void mix_kernel(const float* __restrict__ t5,
                                                  const float* __restrict__ xl,
                                                  const float* __restrict__ s1,
                                                  const float* __restrict__ w2,
                                                  const float* __restrict__ maa,
                                                  __hip_bfloat16* __restrict__ x5b) {
  const int h = blockIdx.x * 256 + threadIdx.x;
  const int t0 = blockIdx.y * 8;
  __shared__ float t5L[8 * 160];
  for (int i = threadIdx.x; i < 8 * 160; i += 256) {
    const int rr = i / 160, cc = i - rr * 160;
    t5L[i] = t5[(size_t)(t0 + rr) * 160 + cc];
  }
  __syncthreads();
  float mixv[8][5];
#pragma unroll
  for (int ts = 0; ts < 8; ts++)
#pragma unroll
    for (int f = 0; f < 5; f++) mixv[ts][f] = 0.f;
#pragma unroll
  for (int f = 0; f < 5; f++) {
#pragma unroll 4
    for (int m = 0; m < 32; m++) {
      const float w2v = w2[(size_t)(f * 32 + m) * HDIM + h];
#pragma unroll
      for (int ts = 0; ts < 8; ts++) mixv[ts][f] += t5L[ts * 160 + f * 32 + m] * w2v;
    }
  }
#pragma unroll
  for (int ts = 0; ts < 8; ts++) {
    const int t = t0 + ts;
    const float cur = xl[(size_t)t * HDIM + h];
    const float past = (t > 0) ? xl[(size_t)(t - 1) * HDIM + h] : s1[h];
    const float sx = past - cur;
#pragma unroll
    for (int f = 0; f < 5; f++) {
      const float v = cur + sx * (mixv[ts][f] + maa[(size_t)f * HDIM + h]);
      x5b[(size_t)f * THE + (size_t)t * HDIM + h] = __float2bfloat16(v);
    }
  }
}

// ---------- batched MFMA GEMM: C[z] = epi( A[z](MxK) @ Bt[z](NxK)^T ) ----------
// epi: 0=bf16 none, 1=bf16 silu, 2=f32 tanh, 3=bf16 tanh, 4=f32 td(+p,clip,exp-exp), 5=f32 +residual
struct GemmArgs {
  const __hip_bfloat16* A[4];
  const __hip_bfloat16* B[4];
  void* C[4];
  const float* aux[4];
  int epi[4];
  int M, N, K;
};

__global__ __launch_bounds__(256) void gemm_bt(GemmArgs ga) {
  const int z = blockIdx.z;
  const __hip_bfloat16* __restrict__ A = ga.A[z];
  const __hip_bfloat16* __restrict__ Bt = ga.B[z];
  const int N = ga.N, K = ga.K;
  const int epi = ga.epi[z];
  const float* __restrict__ aux = ga.aux[z];
  void* Cz = ga.C[z];

  __shared__ __align__(16) __hip_bfloat16 As[128 * 32];
  __shared__ __align__(16) __hip_bfloat16 Bs[128 * 32];

  const int tid = threadIdx.x;
  const int wid = tid >> 6;
  const int lane = tid & 63;

  // XCD-aware swizzle for the 8x16 grids: cluster all 8 m-blocks of one
  // n-panel onto a single XCD so the B panel stays L2-resident.
  int bx = blockIdx.x, by = blockIdx.y;
  if (gridDim.x == 8 && gridDim.y == 16) {
    const int flat = bx + 8 * by;  // 0..127
    const int xcd = flat & 7, rem = flat >> 3;
    bx = rem & 7;
    by = xcd + 8 * (rem >> 3);
  }
  const int m0 = bx * 128;
  const int n0 = by * 128;
  const int wr = wid >> 1, wc = wid & 1;

  const int rsub = lane >> 2;   // 0..15
  const int chunk = lane & 3;   // 0..3
  const int ca = 2 * wid;       // this wave's staging calls: ca, ca+1

  const int arow0 = ca * 16 + rsub;
  const int arow1 = arow0 + 16;
  int brow0 = n0 + arow0; if (brow0 > N - 1) brow0 = N - 1;
  int brow1 = n0 + arow1; if (brow1 > N - 1) brow1 = N - 1;

  const __hip_bfloat16* aSrc0 = A + (size_t)(m0 + arow0) * K + chunk * 8;
  const __hip_bfloat16* aSrc1 = A + (size_t)(m0 + arow1) * K + chunk * 8;
  const __hip_bfloat16* bSrc0 = Bt + (size_t)brow0 * K + chunk * 8;
  const __hip_bfloat16* bSrc1 = Bt + (size_t)brow1 * K + chunk * 8;

  f32x4 acc[4][4];
#pragma unroll
  for (int m = 0; m < 4; m++)
#pragma unroll
    for (int n = 0; n < 4; n++) acc[m][n] = 0.f;

  const int lr = lane & 15;
  const int lk8 = (lane >> 4) * 8;
  const int aoff = (wr * 64 + lr) * 32 + lk8;
  const int boff = (wc * 64 + lr) * 32 + lk8;

  for (int kt = 0; kt < K; kt += 32) {
    gll16(aSrc0 + kt, &As[ca * 512]);
    gll16(aSrc1 + kt, &As[ca * 512 + 512]);
    gll16(bSrc0 + kt, &Bs[ca * 512]);
    gll16(bSrc1 + kt, &Bs[ca * 512 + 512]);
    __syncthreads();
    bf16x8 af[4], bfv[4];
#pragma unroll
    for (int m = 0; m < 4; m++) af[m] = *(const bf16x8*)&As[aoff + m * 16 * 32];
#pragma unroll
    for (int n = 0; n < 4; n++) bfv[n] = *(const bf16x8*)&Bs[boff + n * 16 * 32];
#pragma unroll
    for (int m = 0; m < 4; m++)
#pragma unroll
      for (int n = 0; n < 4; n++)
        acc[m][n] = __builtin_amdgcn_mfma_f32_16x16x32_bf16(af[m], bfv[n], acc[m][n], 0, 0, 0);
    __syncthreads();
  }

  const int r4 = (lane >> 4) * 4;
#pragma unroll
  for (int m = 0; m < 4; m++) {
#pragma unroll
    for (int n = 0; n < 4; n++) {
      const int gn = n0 + wc * 64 + n * 16 + lr;
      if (gn < N) {
#pragma unroll
        for (int r = 0; r < 4; r++) {
          const int gm = m0 + wr * 64 + m * 16 + r4 + r;
          const size_t idx = (size_t)gm * N + gn;
          const float v = acc[m][n][r];
          switch (epi) {
            case 0: ((__hip_bfloat16*)Cz)[idx] = __float2bfloat16(v); break;
            case 1: ((__hip_bfloat16*)Cz)[idx] = __float2bfloat16(v / (1.f + expf(-v))); break;
            case 2: ((float*)Cz)[idx] = tanhf(v); break;
            case 3: ((__hip_bfloat16*)Cz)[idx] = __float2bfloat16(tanhf(v)); break;
            case 4: {
              float wv = v + aux[gn];
              wv = fminf(fmaxf(wv, -9.72f), 2.27f);
              ((float*)Cz)[idx] = expf(-expf(wv));
            } break;
            case 5: ((float*)Cz)[idx] = v + aux[idx]; break;
          }
        }
      }
    }
  }
}

// ---------- decay: rt[c][h][t][j] = r * cumA(t-1)  (bf16) ; Ptot[c][h][j] ----------
__global__ __launch_bounds__(64) void decay_kernel(const __hip_bfloat16* __restrict__ rb,
                                                   const float* __restrict__ td,
                                                   __hip_bfloat16* __restrict__ rt,
                                                   float* __restrict__ Ptot) {
  const int blk = blockIdx.x;  // c*NHEAD + h
  const int c = blk >> 5, h = blk & 31;
  const int j = threadIdx.x;
  const int hb = h * HSZ;
  const int t0 = c * CT;
  float A = 1.f;
  for (int t = 0; t < CT; t++) {
    const size_t rowb = (size_t)(t0 + t) * HDIM + hb;
    rt[(((size_t)c * NHEAD + h) * CT + t) * HSZ + j] =
        __float2bfloat16(__bfloat162float(rb[rowb + j]) * A);
    A *= td[rowb + j];
  }
  Ptot[((size_t)c * NHEAD + h) * HSZ + j] = A;
}

// ---------- single local scan pass: zero-init per chunk; 4-way j-split ----------
// Outputs: wkv_local (f32, excludes diag + s0 terms) and qT[c][h][j][i] (f32).
__global__ __launch_bounds__(256) void scan_local_kernel(const __hip_bfloat16* __restrict__ kb,
                                                         const __hip_bfloat16* __restrict__ rb,
                                                         const float* __restrict__ td,
                                                         const __hip_bfloat16* __restrict__ vb,
                                                         float* __restrict__ wkv,
                                                         float* __restrict__ qT) {
  const int blk = blockIdx.x;           // c*NHEAD + h
  const int c = blk >> 5, h = blk & 31;
  const int w = threadIdx.x >> 6;       // j-quarter 0..3
  const int i = threadIdx.x & 63;       // lane = output row
  __shared__ float plds[2][4][64];

  float s[16];
#pragma unroll
  for (int q = 0; q < 16; q++) s[q] = 0.f;

  const int t0 = c * CT;
  const int hb = h * HSZ;

  for (int t = 0; t < CT; t++) {
    const size_t rowb = (size_t)(t0 + t) * HDIM + hb;
    const unsigned* kw = (const unsigned*)(kb + rowb + w * 16);  // 8 dwords (uniform)
    const unsigned* rw = (const unsigned*)(rb + rowb + w * 16);
    const float* tdw = td + rowb + w * 16;
    const float vi = __bfloat162float(vb[rowb + i]);
    float p = 0.f;
#pragma unroll
    for (int m = 0; m < 8; m++) {
      const unsigned kpair = kw[m];
      const unsigned rpair = rw[m];
      const float k0 = __builtin_bit_cast(float, kpair << 16);
      const float k1 = __builtin_bit_cast(float, kpair & 0xffff0000u);
      const float r0 = __builtin_bit_cast(float, rpair << 16);
      const float r1 = __builtin_bit_cast(float, rpair & 0xffff0000u);
      const float td0 = tdw[2 * m];
      const float td1 = tdw[2 * m + 1];
      const float kv0 = vi * k0;
      const float kv1 = vi * k1;
      p = fmaf(r0, s[2 * m], p);
      p = fmaf(r1, s[2 * m + 1], p);
      s[2 * m] = fmaf(s[2 * m], td0, kv0);
      s[2 * m + 1] = fmaf(s[2 * m + 1], td1, kv1);
    }
    plds[t & 1][w][i] = p;
    __syncthreads();
    if (w == 0) {
      wkv[rowb + i] = plds[t & 1][0][i] + plds[t & 1][1][i] +
                      plds[t & 1][2][i] + plds[t & 1][3][i];
    }
  }
  float* qbase = qT + (((size_t)c * NHEAD + h) * HSZ + w * 16) * HSZ + i;
#pragma unroll
  for (int q = 0; q < 16; q++) qbase[(size_t)q * HSZ] = s[q];
}

// ---------- sequential chunk combine: s0b (bf16) per chunk + s2out ----------
__global__ __launch_bounds__(64) void scan_s_kernel(const float* __restrict__ qT,
                                                    const float* __restrict__ Ptot,
                                                    const float* __restrict__ s2in,
                                                    __hip_bfloat16* __restrict__ s0b,
                                                    float* __restrict__ s2out) {
  const int h = blockIdx.x, i = blockIdx.y, j = threadIdx.x;
  float s = s2in[((size_t)h * HSZ + i) * HSZ + j];
#pragma unroll 4
  for (int c = 0; c < NC; c++) {
    s0b[(((size_t)c * NHEAD + h) * HSZ + i) * HSZ + j] = __float2bfloat16(s);
    s = fmaf(s, Ptot[((size_t)c * NHEAD + h) * HSZ + j],
             qT[(((size_t)c * NHEAD + h) * HSZ + j) * HSZ + i]);
  }
  s2out[((size_t)h * HSZ + i) * HSZ + j] = s;
}

// ---------- correction GEMM: wkv[c*CT+t][h][i] += sum_j rt[t][j] * s0b[i][j] ----------
__global__ __launch_bounds__(256) void corr_kernel(const __hip_bfloat16* __restrict__ rt,
                                                   const __hip_bfloat16* __restrict__ s0b,
                                                   float* __restrict__ wkv) {
  const int c = blockIdx.x, h = blockIdx.y;
  const int w = threadIdx.x >> 6;   // n-tile (i)
  const int lane = threadIdx.x & 63;
  const int lr = lane & 15, lk = (lane >> 4) * 8;
  const __hip_bfloat16* rbase = rt + (((size_t)c * NHEAD + h) * CT) * HSZ;
  const __hip_bfloat16* sbase = s0b + (((size_t)c * NHEAD + h) * HSZ) * HSZ;
  float* wbase = wkv + (size_t)(c * CT) * HDIM + h * HSZ;
#pragma unroll
  for (int mt = 0; mt < CT / 16; mt++) {
    f32x4 acc = {0.f, 0.f, 0.f, 0.f};
#pragma unroll
    for (int ks = 0; ks < 2; ks++) {
      bf16x8 af = *(const bf16x8*)(rbase + (size_t)(mt * 16 + lr) * HSZ + ks * 32 + lk);
      bf16x8 bf = *(const bf16x8*)(sbase + (size_t)(w * 16 + lr) * HSZ + ks * 32 + lk);
      acc = __builtin_amdgcn_mfma_f32_16x16x32_bf16(af, bf, acc, 0, 0, 0);
    }
    const int row = mt * 16 + (lane >> 4) * 4;
    const int col = w * 16 + lr;
#pragma unroll
    for (int r = 0; r < 4; r++)
      wbase[(size_t)(row + r) * HDIM + col] += acc[r];
  }
}

// ---------- group norm over HS (+diag wkv term) + scale/bias + gate ----------
__global__ __launch_bounds__(256) void gnorm_kernel(const float* __restrict__ wkv,
                                                    const __hip_bfloat16* __restrict__ kb,
                                                    const __hip_bfloat16* __restrict__ rb,
                                                    const float* __restrict__ tf,
                                                    const __hip_bfloat16* __restrict__ vb,
                                                    const __hip_bfloat16* __restrict__ gb,
                                                    const float* __restrict__ lnw,
                                                    const float* __restrict__ lnb,
                                                    __hip_bfloat16* __restrict__ yA) {
  const int t = blockIdx.x;
  const int wid = threadIdx.x >> 6, j = threadIdx.x & 63;
  const int h = blockIdx.y * 4 + wid;
  const size_t idx = (size_t)t * HDIM + h * HSZ + j;
  const float kj = __bfloat162float(kb[idx]);
  const float rj = __bfloat162float(rb[idx]);
  const float dg = waveRedSum(rj * tf[h * HSZ + j] * kj);
  const float v = wkv[idx] + dg * __bfloat162float(vb[idx]);
  const float mu = waveRedSum(v) * (1.f / HSZ);
  const float d = v - mu;
  const float var = waveRedSum(d * d) * (1.f / HSZ);
  float y = d * rsqrtf(var + 1e-5f);
  y = y * lnw[h * HSZ + j] + lnb[h * HSZ + j];
  y *= __bfloat162float(gb[idx]);
  yA[idx] = __float2bfloat16(y);
}

extern "C" void kernel_launch(void* const* d_in, const int* in_sizes, int n_in,
                              void* d_out, int out_size, void* d_ws, size_t ws_size,
                              hipStream_t stream) {
  (void)in_sizes; (void)n_in; (void)out_size; (void)ws_size;

  const float* x    = (const float*)d_in[0];
  const float* s1   = (const float*)d_in[1];
  const float* s2   = (const float*)d_in[2];
  const float* ln1w = (const float*)d_in[3];
  const float* ln1b = (const float*)d_in[4];
  const float* tmx  = (const float*)d_in[5];
  const float* tmaa = (const float*)d_in[6];
  const float* w1   = (const float*)d_in[7];
  const float* w2   = (const float*)d_in[8];
  const float* dw1  = (const float*)d_in[9];
  const float* dw2  = (const float*)d_in[10];
  const float* dp   = (const float*)d_in[11];
  const float* tf   = (const float*)d_in[12];
  const float* Wr   = (const float*)d_in[13];
  const float* Wk   = (const float*)d_in[14];
  const float* Wv   = (const float*)d_in[15];
  const float* Wg   = (const float*)d_in[16];
  const float* Wo   = (const float*)d_in[17];
  const float* lnxw = (const float*)d_in[18];
  const float* lnxb = (const float*)d_in[19];

  float* out0  = (float*)d_out;
  float* s1out = out0 + (size_t)TLEN * HDIM;
  float* s2out = s1out + HDIM;

  char* wp = (char*)d_ws;
  size_t off = 0;
  auto carve = [&](size_t bytes) -> void* {
    void* r = wp + off;
    off += (bytes + 255) & ~(size_t)255;
    return r;
  };

  __hip_bfloat16* wrt  = (__hip_bfloat16*)carve((size_t)HDIM * HDIM * 2);
  __hip_bfloat16* wkt  = (__hip_bfloat16*)carve((size_t)HDIM * HDIM * 2);
  __hip_bfloat16* wvt  = (__hip_bfloat16*)carve((size_t)HDIM * HDIM * 2);
  __hip_bfloat16* wgt  = (__hip_bfloat16*)carve((size_t)HDIM * HDIM * 2);
  __hip_bfloat16* wot  = (__hip_bfloat16*)carve((size_t)HDIM * HDIM * 2);
  __hip_bfloat16* w1t  = (__hip_bfloat16*)carve((size_t)160 * HDIM * 2);
  __hip_bfloat16* dw1t = (__hip_bfloat16*)carve((size_t)64 * HDIM * 2);
  __hip_bfloat16* dw2t = (__hip_bfloat16*)carve((size_t)HDIM * 64 * 2);
  float* xl            = (float*)carve((size_t)THE * 4);
  __hip_bfloat16* xxx  = (__hip_bfloat16*)carve((size_t)THE * 2);
  float* t5            = (float*)carve((size_t)TLEN * 160 * 4);
  __hip_bfloat16* x5b  = (__hip_bfloat16*)carve((size_t)5 * THE * 2);
  __hip_bfloat16* rb   = (__hip_bfloat16*)carve((size_t)THE * 2);
  __hip_bfloat16* kb   = (__hip_bfloat16*)carve((size_t)THE * 2);
  __hip_bfloat16* vb   = (__hip_bfloat16*)carve((size_t)THE * 2);
  __hip_bfloat16* gb   = (__hip_bfloat16*)carve((size_t)THE * 2);
  __hip_bfloat16* tw   = (__hip_bfloat16*)carve((size_t)TLEN * 64 * 2);
  float* td            = (float*)carve((size_t)THE * 4);
  float* wkv           = (float*)carve((size_t)THE * 4);
  __hip_bfloat16* yA   = (__hip_bfloat16*)carve((size_t)THE * 2);

  // Scan-stage buffers alias dead regions (zero extra workspace):
  //   qT   (16MB) <- x5b (20MB, dead after G4/G5)
  //   rt   ( 4MB) <- xl  (8MB, dead after mix)
  //   s0b  ( 8MB) <- td  (dead after scan_local)
  //   Ptot (256KB)<- t5  (640KB, dead after mix)
  float* qT            = (float*)x5b;
  __hip_bfloat16* rt   = (__hip_bfloat16*)xl;
  __hip_bfloat16* s0b  = (__hip_bfloat16*)td;
  float* Ptot          = (float*)t5;

  // K0: convert + transpose all GEMM weights to bf16 [N][K]
  TrArgs ta;
  const float* srcs[8] = {Wr, Wk, Wv, Wg, Wo, w1, dw1, dw2};
  __hip_bfloat16* dsts[8] = {wrt, wkt, wvt, wgt, wot, w1t, dw1t, dw2t};
  const int Rs[8] = {HDIM, HDIM, HDIM, HDIM, HDIM, HDIM, HDIM, 64};
  const int Cs[8] = {HDIM, HDIM, HDIM, HDIM, HDIM, 160, 64, HDIM};
  for (int z = 0; z < 8; z++) { ta.src[z] = srcs[z]; ta.dst[z] = dsts[z]; ta.R[z] = Rs[z]; ta.C[z] = Cs[z]; }
  transp_kernel<<<dim3(64, 64, 8), 256, 0, stream>>>(ta);

  // K1: layernorm
  ln1_kernel<<<dim3(TLEN), 256, 0, stream>>>(x, ln1w, ln1b, xl, s1out);

  // K2: token shift -> xxx (bf16)
  tokshift_kernel<<<dim3(TLEN, HDIM / 256), 256, 0, stream>>>(xl, s1, tmx, xxx);

  // G1: t5 = tanh(xxx @ w1)  (M=1024, N=160, K=2048)
  {
    GemmArgs g{};
    g.A[0] = xxx; g.B[0] = w1t; g.C[0] = t5; g.aux[0] = nullptr; g.epi[0] = 2;
    g.M = TLEN; g.N = 160; g.K = HDIM;
    gemm_bt<<<dim3(TLEN / 128, 2, 1), 256, 0, stream>>>(g);
  }

  // K4: mix + x5 (5 planes, bf16)
  mix_kernel<<<dim3(HDIM / 256, TLEN / 8), 256, 0, stream>>>(t5, xl, s1, w2, tmaa, x5b);

  // G2: r, k, v, g  (batched z=4)
  {
    GemmArgs g{};
    g.A[0] = x5b + (size_t)3 * THE; g.B[0] = wrt; g.C[0] = rb; g.epi[0] = 0;
    g.A[1] = x5b + (size_t)1 * THE; g.B[1] = wkt; g.C[1] = kb; g.epi[1] = 0;
    g.A[2] = x5b + (size_t)2 * THE; g.B[2] = wvt; g.C[2] = vb; g.epi[2] = 0;
    g.A[3] = x5b + (size_t)4 * THE; g.B[3] = wgt; g.C[3] = gb; g.epi[3] = 1;
    g.M = TLEN; g.N = HDIM; g.K = HDIM;
    gemm_bt<<<dim3(TLEN / 128, HDIM / 128, 4), 256, 0, stream>>>(g);
  }

  // G4: tw = tanh(mw @ dw1)  (N=64)
  {
    GemmArgs g{};
    g.A[0] = x5b; g.B[0] = dw1t; g.C[0] = tw; g.epi[0] = 3;
    g.M = TLEN; g.N = 64; g.K = HDIM;
    gemm_bt<<<dim3(TLEN / 128, 1, 1), 256, 0, stream>>>(g);
  }

  // G5: td = exp(-exp(clip(tw @ dw2 + p)))  (K=64)
  {
    GemmArgs g{};
    g.A[0] = tw; g.B[0] = dw2t; g.C[0] = td; g.aux[0] = dp; g.epi[0] = 4;
    g.M = TLEN; g.N = HDIM; g.K = 64;
    gemm_bt<<<dim3(TLEN / 128, HDIM / 128, 1), 256, 0, stream>>>(g);
  }

  // Scan stage: decay factors, single local pass, chunk combine, MFMA correction
  decay_kernel<<<dim3(NC * NHEAD), 64, 0, stream>>>(rb, td, rt, Ptot);
  scan_local_kernel<<<dim3(NC * NHEAD), 256, 0, stream>>>(kb, rb, td, vb, wkv, qT);
  scan_s_kernel<<<dim3(NHEAD, HSZ), 64, 0, stream>>>(qT, Ptot, s2, s0b, s2out);
  corr_kernel<<<dim3(NC, NHEAD), 256, 0, stream>>>(rt, s0b, wkv);

  // K7: group-norm (+diag term) + gate -> yA (bf16)
  gnorm_kernel<<<dim3(TLEN, NHEAD / 4), 256, 0, stream>>>(wkv, kb, rb, tf, vb, gb, lnxw, lnxb, yA);

  // G6: out = x + yA @ W_o
  {
    GemmArgs g{};
    g.A[0] = yA; g.B[0] = wot; g.C[0] = out0; g.aux[0] = x; g.epi[0] = 5;
    g.M = TLEN; g.N = HDIM; g.K = HDIM;
    gemm_bt<<<dim3(TLEN / 128, HDIM / 128, 1), 256, 0, stream>>>(g);
  }
}